// Round 1
// baseline (931.705 us; speedup 1.0000x reference)
//
#include <hip/hip_runtime.h>
#include <math.h>

// Problem constants (fixed by setup_inputs)
#define NB     128      // batches/graphs
#define NNODE  64       // nodes per graph
#define NTOT   8192     // N = NB*NNODE
#define DIM    64       // D

__device__ __forceinline__ float silu_f(float x) {
    return x / (1.0f + __expf(-x));
}

__device__ __forceinline__ float wsum(float v) {
    #pragma unroll
    for (int m = 1; m < 64; m <<= 1) v += __shfl_xor(v, m, 64);
    return v;
}

__device__ __forceinline__ float wmax(float v) {
    #pragma unroll
    for (int m = 1; m < 64; m <<= 1) v = fmaxf(v, __shfl_xor(v, m, 64));
    return v;
}

// ---------------------------------------------------------------------------
// K1: per-batch mean of ||X||, Xn = w * X / (mean_norm + 1e-5)
// grid: NB blocks x 64 threads (one thread per node in batch)
// ---------------------------------------------------------------------------
__global__ void k1_xnorm(const float* __restrict__ X,
                         const float* __restrict__ xw,
                         float* __restrict__ Xn) {
    const int b = blockIdx.x;
    const int L = threadIdx.x;
    const int n = b * NNODE + L;
    const float x0 = X[n*3+0], x1 = X[n*3+1], x2 = X[n*3+2];
    const float nm = sqrtf(x0*x0 + x1*x1 + x2*x2);
    const float mean = wsum(nm) * (1.0f / 64.0f);
    const float sc = xw[0] / (mean + 1e-5f);
    Xn[n*3+0] = x0 * sc;
    Xn[n*3+1] = x1 * sc;
    Xn[n*3+2] = x2 * sc;
}

// ---------------------------------------------------------------------------
// K2: per-node Qn = LN(silu(H@q_w1)@q_w2)*qnw+qnb, P = H @ kv_w1[1:,:]
// grid: NTOT/4 blocks x 256 threads (wave per node)
// ---------------------------------------------------------------------------
__global__ __launch_bounds__(256) void k2_node(
        const float* __restrict__ H,
        const float* __restrict__ qw1, const float* __restrict__ qw2,
        const float* __restrict__ kvw1,
        const float* __restrict__ qnw, const float* __restrict__ qnb,
        float* __restrict__ Qn, float* __restrict__ Pt) {
    const int w = threadIdx.x >> 6, L = threadIdx.x & 63;
    const int n = blockIdx.x * 4 + w;
    __shared__ float hs[4][64];
    __shared__ float q1s[4][64];
    const float h = H[n*DIM + L];
    hs[w][L] = h;
    __syncthreads();
    float acc = 0.f;
    #pragma unroll 8
    for (int j = 0; j < 64; ++j) acc += hs[w][j] * qw1[j*64 + L];
    q1s[w][L] = silu_f(acc);
    __syncthreads();
    float a2 = 0.f;
    #pragma unroll 8
    for (int j = 0; j < 64; ++j) a2 += q1s[w][j] * qw2[j*64 + L];
    const float mu = wsum(a2) * (1.0f/64.0f);
    const float m2 = wsum(a2*a2) * (1.0f/64.0f);
    const float rstd = rsqrtf(m2 - mu*mu + 1e-5f);
    Qn[n*DIM + L] = (a2 - mu) * rstd * qnw[L] + qnb[L];
    float p0 = 0.f, p1 = 0.f;
    #pragma unroll 8
    for (int c = 0; c < 64; ++c) {
        const float hv = hs[w][c];
        p0 += hv * kvw1[(1+c)*128 + L];
        p1 += hv * kvw1[(1+c)*128 + 64 + L];
    }
    Pt[n*128 + L]      = p0;
    Pt[n*128 + 64 + L] = p1;
}

// ---------------------------------------------------------------------------
// K3: per-dst fused edge pipeline (the big one).
// grid: NTOT blocks x 256 threads (4 waves). Wave w owns output cols
// [16w,16w+16); lane-group q=L>>4 owns j-quarter of the contraction;
// kv_w2 / phx_w1 slices live in registers (80 f32/lane).
// ---------------------------------------------------------------------------
__global__ __launch_bounds__(256, 3) void k3_edge(
        const float* __restrict__ Xn, const float* __restrict__ Qn,
        const float* __restrict__ Pt,
        const float* __restrict__ kvw1, const float* __restrict__ kvw2,
        const float* __restrict__ knw, const float* __restrict__ knb,
        const float* __restrict__ phxw1, const float* __restrict__ phxw2,
        float* __restrict__ Abuf, float* __restrict__ Xout) {
    const int d  = blockIdx.x;
    const int g  = d >> 6, dl = d & 63, gb = g << 6;
    const int T  = threadIdx.x;
    const int w  = T >> 6, L = T & 63;
    const int c  = L & 15, q = L >> 4;
    const int col = (w << 4) + c;

    __shared__ __align__(16) float t_s[144];        // 4 quarters, padded to 36
    __shared__ float K_s[64];
    __shared__ __align__(16) float V_s[64][64];
    __shared__ float G_s[64][64];
    __shared__ float sc_s[64];
    __shared__ float al_s[64];
    __shared__ float rd_s[64];
    __shared__ float xr_s[64][3];
    __shared__ float w0_s[128];
    __shared__ float xp_s[12];

    // register-resident weight slices
    float wK[32], wV[32], wG16[16];
    #pragma unroll
    for (int jj = 0; jj < 32; ++jj) {
        wK[jj] = kvw2[(q*32 + jj)*128 + col];
        wV[jj] = kvw2[(q*32 + jj)*128 + 64 + col];
    }
    #pragma unroll
    for (int kk = 0; kk < 16; ++kk)
        wG16[kk] = phxw1[(q*16 + kk)*64 + col];

    const float qd  = Qn[d*DIM + L];
    const float kw  = knw[L], kb = knb[L];
    const float pw2 = phxw2[L];
    const float xd0 = Xn[d*3+0], xd1 = Xn[d*3+1], xd2 = Xn[d*3+2];

    if (T < 64) {
        const int n = gb + T;
        const float r0 = Xn[n*3+0]-xd0, r1 = Xn[n*3+1]-xd1, r2 = Xn[n*3+2]-xd2;
        const float rd = r0*r0 + r1*r1 + r2*r2;
        rd_s[T] = rd;
        const float inv = 1.0f / (1.0f + sqrtf(rd + 1e-8f));
        xr_s[T][0] = r0*inv; xr_s[T][1] = r1*inv; xr_s[T][2] = r2*inv;
    } else if (T < 192) {
        w0_s[T-64] = kvw1[T-64];     // kv_w1 row 0
    }
    __syncthreads();

    for (int s = 0; s < 64; ++s) {
        // --- phase A: t = silu(P[src] + rd * w0) ---
        if (T < 128) {
            const int j = T;
            const float v = Pt[(gb + s)*128 + j] + rd_s[s] * w0_s[j];
            t_s[(j >> 5)*36 + (j & 31)] = silu_f(v);
        }
        __syncthreads();

        // --- phase B: K,V partials over this lane-group's j-quarter ---
        const float4* tq = (const float4*)&t_s[q*36];
        float ka = 0.f, va = 0.f;
        #pragma unroll
        for (int b = 0; b < 8; ++b) {
            const float4 tv = tq[b];
            ka += tv.x*wK[4*b+0]; va += tv.x*wV[4*b+0];
            ka += tv.y*wK[4*b+1]; va += tv.y*wV[4*b+1];
            ka += tv.z*wK[4*b+2]; va += tv.z*wV[4*b+2];
            ka += tv.w*wK[4*b+3]; va += tv.w*wV[4*b+3];
        }
        ka += __shfl_xor(ka, 16, 64); ka += __shfl_xor(ka, 32, 64);
        va += __shfl_xor(va, 16, 64); va += __shfl_xor(va, 32, 64);
        if (L < 16)      K_s[col]    = ka;
        else if (L < 32) V_s[s][col] = va;
        __syncthreads();

        // --- phase C: G = V @ phx_w1 ; wave0 also LN(K) + score ---
        const float4* vq = (const float4*)&V_s[s][q*16];
        float ga = 0.f;
        #pragma unroll
        for (int b = 0; b < 4; ++b) {
            const float4 vv = vq[b];
            ga += vv.x*wG16[4*b+0] + vv.y*wG16[4*b+1]
                + vv.z*wG16[4*b+2] + vv.w*wG16[4*b+3];
        }
        ga += __shfl_xor(ga, 16, 64); ga += __shfl_xor(ga, 32, 64);
        if (L < 16) G_s[s][col] = ga;

        if (w == 0) {
            const float kvl = K_s[L];
            const float mu  = wsum(kvl) * (1.0f/64.0f);
            const float m2  = wsum(kvl*kvl) * (1.0f/64.0f);
            const float rstd = rsqrtf(m2 - mu*mu + 1e-5f);
            const float kn = (kvl - mu) * rstd * kw + kb;
            const float sc = wsum(qd * kn) * 0.125f;       // /sqrt(64)
            if (L == 0) sc_s[s] = (s == dl) ? -1e30f : sc;
        }
        __syncthreads();
    }

    // --- softmax over srcs (exact; masked diagonal contributes 0) ---
    if (w == 0) {
        const float sc = sc_s[L];
        const float m = wmax(sc);
        const float e = __expf(sc - m);
        const float S = wsum(e);
        al_s[L] = e / S;
    }
    __syncthreads();

    // --- X accumulation: wave w handles srcs [16w,16w+16) ---
    float xa0 = 0.f, xa1 = 0.f, xa2 = 0.f;
    for (int k = 0; k < 16; ++k) {
        const int s = (w << 4) + k;
        const float a  = al_s[s];
        const float ph = wsum(silu_f(a * G_s[s][L]) * pw2);
        xa0 += ph * xr_s[s][0];
        xa1 += ph * xr_s[s][1];
        xa2 += ph * xr_s[s][2];
    }
    if (L == 0) { xp_s[w*3+0] = xa0; xp_s[w*3+1] = xa1; xp_s[w*3+2] = xa2; }
    __syncthreads();

    // --- A = sum_s alpha_s * V_s ---
    if (w == 0) {
        float acc = 0.f;
        #pragma unroll 8
        for (int s2 = 0; s2 < 64; ++s2) acc += al_s[s2] * V_s[s2][L];
        Abuf[d*DIM + L] = acc;
    }
    if (T == 0) {
        Xout[d*3+0] = xd0 + xp_s[0] + xp_s[3] + xp_s[6] + xp_s[9];
        Xout[d*3+1] = xd1 + xp_s[1] + xp_s[4] + xp_s[7] + xp_s[10];
        Xout[d*3+2] = xd2 + xp_s[2] + xp_s[5] + xp_s[8] + xp_s[11];
    }
}

// ---------------------------------------------------------------------------
// K4: H_out = H + silu((A*A*H) @ phh_w1 + b1) @ phh_w2 + b2
// (uses AH = A ⊙ H  =>  A*AH = A² ⊙ H)
// ---------------------------------------------------------------------------
__global__ __launch_bounds__(256) void k4_hout(
        const float* __restrict__ H, const float* __restrict__ Abuf,
        const float* __restrict__ w1, const float* __restrict__ b1,
        const float* __restrict__ w2, const float* __restrict__ b2,
        float* __restrict__ Hout) {
    const int w = threadIdx.x >> 6, L = threadIdx.x & 63;
    const int n = blockIdx.x * 4 + w;
    __shared__ float us[4][64];
    __shared__ float ss[4][64];
    const float h = H[n*DIM + L];
    const float a = Abuf[n*DIM + L];
    us[w][L] = a * a * h;
    __syncthreads();
    float z = b1[L];
    #pragma unroll 8
    for (int k = 0; k < 64; ++k) z += us[w][k] * w1[k*64 + L];
    ss[w][L] = silu_f(z);
    __syncthreads();
    float r = b2[L];
    #pragma unroll 8
    for (int j = 0; j < 64; ++j) r += ss[w][j] * w2[j*64 + L];
    Hout[n*DIM + L] = h + r;
}

// ---------------------------------------------------------------------------
extern "C" void kernel_launch(void* const* d_in, const int* in_sizes, int n_in,
                              void* d_out, int out_size, void* d_ws, size_t ws_size,
                              hipStream_t stream) {
    const float* X    = (const float*)d_in[1];
    const float* H    = (const float*)d_in[2];
    const float* xw   = (const float*)d_in[4];
    const float* qw1  = (const float*)d_in[5];
    const float* qw2  = (const float*)d_in[6];
    const float* kvw1 = (const float*)d_in[7];
    const float* kvw2 = (const float*)d_in[8];
    const float* qnw  = (const float*)d_in[9];
    const float* qnb  = (const float*)d_in[10];
    const float* knw  = (const float*)d_in[11];
    const float* knb  = (const float*)d_in[12];
    const float* pxw1 = (const float*)d_in[13];
    const float* pxw2 = (const float*)d_in[14];
    const float* phw1 = (const float*)d_in[15];
    const float* phb1 = (const float*)d_in[16];
    const float* phw2 = (const float*)d_in[17];
    const float* phb2 = (const float*)d_in[18];

    float* out = (float*)d_out;
    char*  ws  = (char*)d_ws;

    // workspace layout (all fp32): Xn[N*3] | Qn[N*64] | P[N*128] | A[N*64]
    float* Xn = (float*)(ws);
    float* Qn = (float*)(ws + (size_t)NTOT*3*4);
    float* Pt = (float*)(ws + (size_t)NTOT*3*4 + (size_t)NTOT*64*4);
    float* Ab = (float*)(ws + (size_t)NTOT*3*4 + (size_t)NTOT*64*4 + (size_t)NTOT*128*4);

    k1_xnorm<<<NB, 64, 0, stream>>>(X, xw, Xn);
    k2_node<<<NTOT/4, 256, 0, stream>>>(H, qw1, qw2, kvw1, qnw, qnb, Qn, Pt);
    k3_edge<<<NTOT, 256, 0, stream>>>(Xn, Qn, Pt, kvw1, kvw2, knw, knb,
                                      pxw1, pxw2, Ab, out);
    k4_hout<<<NTOT/4, 256, 0, stream>>>(H, Ab, phw1, phb1, phw2, phb2,
                                        out + NTOT*3);
}

// Round 2
// 312.566 us; speedup vs baseline: 2.9808x; 2.9808x over previous
//
#include <hip/hip_runtime.h>
#include <math.h>

// Problem constants (fixed by setup_inputs)
#define NB     128
#define NNODE  64
#define NTOT   8192
#define DIM    64

typedef __bf16 bf16x8 __attribute__((ext_vector_type(8)));
typedef float  f32x4  __attribute__((ext_vector_type(4)));

__device__ __forceinline__ float silu_f(float x) {
    return x / (1.0f + __expf(-x));
}

__device__ __forceinline__ unsigned short bf16bits(float f) {
    return __builtin_bit_cast(unsigned short, (__bf16)f);
}

__device__ __forceinline__ float wsum(float v) {
    #pragma unroll
    for (int m = 1; m < 64; m <<= 1) v += __shfl_xor(v, m, 64);
    return v;
}

__device__ __forceinline__ float wmax(float v) {
    #pragma unroll
    for (int m = 1; m < 64; m <<= 1) v = fmaxf(v, __shfl_xor(v, m, 64));
    return v;
}

// ---------------------------------------------------------------------------
// K0: prep transposed bf16 weights in ws:
//   w2T[n][k], n<128, k<128, stride 136 bf16  (kvw2 is [k][n] row-major)
//   x1T[n][k], n<64,  k<64,  stride 72  bf16  (phxw1 is [k][n] row-major)
// ---------------------------------------------------------------------------
__global__ void k0_prep(const float* __restrict__ kvw2,
                        const float* __restrict__ phxw1,
                        unsigned short* __restrict__ w2T,
                        unsigned short* __restrict__ x1T) {
    const int idx = blockIdx.x * 256 + threadIdx.x;   // 0..16383
    const int k = idx >> 7, n = idx & 127;
    w2T[n*136 + k] = bf16bits(kvw2[k*128 + n]);
    if (idx < 4096) {
        const int k2 = idx >> 6, n2 = idx & 63;
        x1T[n2*72 + k2] = bf16bits(phxw1[k2*64 + n2]);
    }
}

// ---------------------------------------------------------------------------
// K1: per-batch mean of ||X||, Xn = w * X / (mean_norm + 1e-5)
// ---------------------------------------------------------------------------
__global__ void k1_xnorm(const float* __restrict__ X,
                         const float* __restrict__ xw,
                         float* __restrict__ Xn) {
    const int b = blockIdx.x;
    const int L = threadIdx.x;
    const int n = b * NNODE + L;
    const float x0 = X[n*3+0], x1 = X[n*3+1], x2 = X[n*3+2];
    const float nm = sqrtf(x0*x0 + x1*x1 + x2*x2);
    const float mean = wsum(nm) * (1.0f / 64.0f);
    const float sc = xw[0] / (mean + 1e-5f);
    Xn[n*3+0] = x0 * sc;
    Xn[n*3+1] = x1 * sc;
    Xn[n*3+2] = x2 * sc;
}

// ---------------------------------------------------------------------------
// K2: per-node Qn = LN(silu(H@q_w1)@q_w2)*qnw+qnb, P = H @ kv_w1[1:,:]
// ---------------------------------------------------------------------------
__global__ __launch_bounds__(256) void k2_node(
        const float* __restrict__ H,
        const float* __restrict__ qw1, const float* __restrict__ qw2,
        const float* __restrict__ kvw1,
        const float* __restrict__ qnw, const float* __restrict__ qnb,
        float* __restrict__ Qn, float* __restrict__ Pt) {
    const int w = threadIdx.x >> 6, L = threadIdx.x & 63;
    const int n = blockIdx.x * 4 + w;
    __shared__ float hs[4][64];
    __shared__ float q1s[4][64];
    const float h = H[n*DIM + L];
    hs[w][L] = h;
    __syncthreads();
    float acc = 0.f;
    #pragma unroll 8
    for (int j = 0; j < 64; ++j) acc += hs[w][j] * qw1[j*64 + L];
    q1s[w][L] = silu_f(acc);
    __syncthreads();
    float a2 = 0.f;
    #pragma unroll 8
    for (int j = 0; j < 64; ++j) a2 += q1s[w][j] * qw2[j*64 + L];
    const float mu = wsum(a2) * (1.0f/64.0f);
    const float m2 = wsum(a2*a2) * (1.0f/64.0f);
    const float rstd = rsqrtf(m2 - mu*mu + 1e-5f);
    Qn[n*DIM + L] = (a2 - mu) * rstd * qnw[L] + qnb[L];
    float p0 = 0.f, p1 = 0.f;
    #pragma unroll 8
    for (int c = 0; c < 64; ++c) {
        const float hv = hs[w][c];
        p0 += hv * kvw1[(1+c)*128 + L];
        p1 += hv * kvw1[(1+c)*128 + 64 + L];
    }
    Pt[n*128 + L]      = p0;
    Pt[n*128 + 64 + L] = p1;
}

// ---------------------------------------------------------------------------
// K3: per-dst fused edge pipeline, MFMA version.
//   GEMM1: KV(64x128) = t(64x128) @ kvw2(128x128)   [128 mfma_16x16x32_bf16]
//   GEMM2: G(64x64)   = V(64x64)  @ phxw1(64x64)    [32 mfma]
// Fragment conventions (verified, learn_hip m89/m91):
//   A: lane holds A[m=L&15][k=(L>>4)*8+j]; B: B[k=(L>>4)*8+j][n=L&15]
//   D: D[(L>>4)*4+reg][L&15]
// ---------------------------------------------------------------------------
__global__ __launch_bounds__(256, 2) void k3_edge(
        const float* __restrict__ Xn, const float* __restrict__ Qn,
        const float* __restrict__ Pt,
        const unsigned short* __restrict__ w2T,
        const unsigned short* __restrict__ x1T,
        const float* __restrict__ knw, const float* __restrict__ knb,
        const float* __restrict__ pxw2, const float* __restrict__ kvw1,
        float* __restrict__ Abuf, float* __restrict__ Xout) {
    const int d  = blockIdx.x;
    const int dl = d & 63, gb = d & ~63;
    const int T  = threadIdx.x;
    const int w  = T >> 6, L = T & 63;
    const int q  = L >> 4, m = L & 15;

    __shared__ __align__(16) unsigned short sw2[128*136];   // 34816 B
    __shared__ __align__(16) unsigned short tK[64*136];     // t bf16 -> K fp32 (17408 B)
    __shared__ __align__(16) unsigned short sV[64*72];      // 9216 B
    __shared__ __align__(16) unsigned short sx1[64*72];     // 9216 B
    __shared__ float qd_s[64], w0_s[128], knw_s[64], knb_s[64], px_s[64];
    __shared__ float rd_s[64], xr_s[64][3], sc_s[64], al_s[64];
    __shared__ float phacc[64][4];
    __shared__ float Apart[4][64];

    unsigned short* t_s = tK;
    float* K_s = (float*)tK;      // stride 68 words (same 17408 bytes)

    const float xd0 = Xn[d*3+0], xd1 = Xn[d*3+1], xd2 = Xn[d*3+2];

    // ---- stage transposed weights (bf16, already padded in global) ----
    {
        const uint4* gw2 = (const uint4*)w2T;
        uint4* lw2 = (uint4*)sw2;
        #pragma unroll
        for (int i = 0; i < 9; ++i) {
            const int idx = T + 256*i;
            if (idx < 2176) lw2[idx] = gw2[idx];
        }
        const uint4* gx1 = (const uint4*)x1T;
        uint4* lx1 = (uint4*)sx1;
        #pragma unroll
        for (int i = 0; i < 3; ++i) {
            const int idx = T + 256*i;
            if (idx < 576) lx1[idx] = gx1[idx];
        }
    }

    if (T < 64) {
        const int n = gb + T;
        const float r0 = Xn[n*3+0]-xd0, r1 = Xn[n*3+1]-xd1, r2 = Xn[n*3+2]-xd2;
        const float rd = r0*r0 + r1*r1 + r2*r2;
        rd_s[T] = rd;
        const float inv = 1.0f / (1.0f + sqrtf(rd + 1e-8f));
        xr_s[T][0] = r0*inv; xr_s[T][1] = r1*inv; xr_s[T][2] = r2*inv;
        qd_s[T]  = Qn[d*DIM + T];
        knw_s[T] = knw[T];
        knb_s[T] = knb[T];
        px_s[T]  = pxw2[T];
    } else if (T < 192) {
        w0_s[T-64] = kvw1[T-64];
    }
    __syncthreads();

    // ---- t = silu(P[src] + rd*w0) in bf16, row stride 136 ----
    {
        const int s = T >> 2, j0 = (T & 3) * 32;
        const float rd = rd_s[s];
        const float4* prow = (const float4*)&Pt[(size_t)(gb + s)*128 + j0];
        #pragma unroll
        for (int bb = 0; bb < 4; ++bb) {
            const float4 p0 = prow[2*bb], p1 = prow[2*bb+1];
            const float* wp = &w0_s[j0 + 8*bb];
            const float v0 = silu_f(p0.x + rd*wp[0]);
            const float v1 = silu_f(p0.y + rd*wp[1]);
            const float v2 = silu_f(p0.z + rd*wp[2]);
            const float v3 = silu_f(p0.w + rd*wp[3]);
            const float v4 = silu_f(p1.x + rd*wp[4]);
            const float v5 = silu_f(p1.y + rd*wp[5]);
            const float v6 = silu_f(p1.z + rd*wp[6]);
            const float v7 = silu_f(p1.w + rd*wp[7]);
            uint4 pk;
            pk.x = (unsigned)bf16bits(v0) | ((unsigned)bf16bits(v1) << 16);
            pk.y = (unsigned)bf16bits(v2) | ((unsigned)bf16bits(v3) << 16);
            pk.z = (unsigned)bf16bits(v4) | ((unsigned)bf16bits(v5) << 16);
            pk.w = (unsigned)bf16bits(v6) | ((unsigned)bf16bits(v7) << 16);
            *(uint4*)&t_s[s*136 + j0 + 8*bb] = pk;
        }
    }
    __syncthreads();

    // ---- GEMM1: acc[ct][rt] = C tile, wave w owns cols [32w, 32w+32) ----
    f32x4 acc[2][4];
    #pragma unroll
    for (int ct = 0; ct < 2; ++ct)
        #pragma unroll
        for (int rt = 0; rt < 4; ++rt)
            acc[ct][rt] = (f32x4){0.f, 0.f, 0.f, 0.f};

    #pragma unroll
    for (int ks = 0; ks < 4; ++ks) {
        bf16x8 a[4];
        #pragma unroll
        for (int rt = 0; rt < 4; ++rt)
            a[rt] = *(const bf16x8*)&t_s[(rt*16 + m)*136 + ks*32 + q*8];
        const bf16x8 b0 = *(const bf16x8*)&sw2[(32*w      + m)*136 + ks*32 + q*8];
        const bf16x8 b1 = *(const bf16x8*)&sw2[(32*w + 16 + m)*136 + ks*32 + q*8];
        #pragma unroll
        for (int rt = 0; rt < 4; ++rt)
            acc[0][rt] = __builtin_amdgcn_mfma_f32_16x16x32_bf16(a[rt], b0, acc[0][rt], 0, 0, 0);
        #pragma unroll
        for (int rt = 0; rt < 4; ++rt)
            acc[1][rt] = __builtin_amdgcn_mfma_f32_16x16x32_bf16(a[rt], b1, acc[1][rt], 0, 0, 0);
    }
    __syncthreads();   // t_s reads complete; reuse the space for K fp32

    // ---- write out: waves 0,1 -> K fp32; waves 2,3 -> V bf16 (pair-packed) ----
    if (w < 2) {
        #pragma unroll
        for (int ct = 0; ct < 2; ++ct)
            #pragma unroll
            for (int rt = 0; rt < 4; ++rt)
                #pragma unroll
                for (int r = 0; r < 4; ++r)
                    K_s[(rt*16 + q*4 + r)*68 + w*32 + ct*16 + m] = acc[ct][rt][r];
    } else {
        #pragma unroll
        for (int ct = 0; ct < 2; ++ct)
            #pragma unroll
            for (int rt = 0; rt < 4; ++rt)
                #pragma unroll
                for (int r = 0; r < 4; ++r) {
                    const unsigned u = bf16bits(acc[ct][rt][r]);
                    const unsigned o = __shfl_xor(u, 1, 64);
                    if ((L & 1) == 0) {
                        *(unsigned*)&sV[(rt*16 + q*4 + r)*72 + (w-2)*32 + ct*16 + m]
                            = u | (o << 16);
                    }
                }
    }
    __syncthreads();

    // ---- GEMM2: g[rt] = G tile, wave w owns cols [16w, 16w+16) ----
    f32x4 g[4];
    #pragma unroll
    for (int rt = 0; rt < 4; ++rt) g[rt] = (f32x4){0.f, 0.f, 0.f, 0.f};
    #pragma unroll
    for (int ks = 0; ks < 2; ++ks) {
        bf16x8 a[4];
        #pragma unroll
        for (int rt = 0; rt < 4; ++rt)
            a[rt] = *(const bf16x8*)&sV[(rt*16 + m)*72 + ks*32 + q*8];
        const bf16x8 b = *(const bf16x8*)&sx1[(16*w + m)*72 + ks*32 + q*8];
        #pragma unroll
        for (int rt = 0; rt < 4; ++rt)
            g[rt] = __builtin_amdgcn_mfma_f32_16x16x32_bf16(a[rt], b, g[rt], 0, 0, 0);
    }

    // ---- LN(K) + score, 4 lanes per row ----
    {
        const int row = 16*w + (L >> 2), j0 = (L & 3)*16;
        float kv[16];
        float sum = 0.f, sq = 0.f;
        #pragma unroll
        for (int bb = 0; bb < 4; ++bb) {
            const float4 kk = *(const float4*)&K_s[row*68 + j0 + bb*4];
            kv[4*bb+0] = kk.x; kv[4*bb+1] = kk.y; kv[4*bb+2] = kk.z; kv[4*bb+3] = kk.w;
            sum += kk.x + kk.y + kk.z + kk.w;
            sq  += kk.x*kk.x + kk.y*kk.y + kk.z*kk.z + kk.w*kk.w;
        }
        sum += __shfl_xor(sum, 1, 64); sum += __shfl_xor(sum, 2, 64);
        sq  += __shfl_xor(sq,  1, 64); sq  += __shfl_xor(sq,  2, 64);
        const float mu = sum * (1.0f/64.0f);
        const float rstd = rsqrtf(sq * (1.0f/64.0f) - mu*mu + 1e-5f);
        float sp = 0.f;
        #pragma unroll
        for (int e = 0; e < 16; ++e)
            sp += ((kv[e] - mu)*rstd*knw_s[j0+e] + knb_s[j0+e]) * qd_s[j0+e];
        sp += __shfl_xor(sp, 1, 64); sp += __shfl_xor(sp, 2, 64);
        if ((L & 3) == 0) sc_s[row] = (row == dl) ? -1e30f : sp * 0.125f;
    }
    __syncthreads();

    // ---- softmax over the 64 srcs ----
    if (w == 0) {
        const float sc = sc_s[L];
        const float mx = wmax(sc);
        const float e  = __expf(sc - mx);
        const float S  = wsum(e);
        al_s[L] = e / S;
    }
    __syncthreads();

    // ---- phx partials from G fragments ----
    {
        const float px = px_s[16*w + m];
        #pragma unroll
        for (int rt = 0; rt < 4; ++rt)
            #pragma unroll
            for (int r = 0; r < 4; ++r) {
                const int row = rt*16 + q*4 + r;
                float v = silu_f(al_s[row] * g[rt][r]) * px;
                v += __shfl_xor(v, 1, 64);
                v += __shfl_xor(v, 2, 64);
                v += __shfl_xor(v, 4, 64);
                v += __shfl_xor(v, 8, 64);
                if (m == 0) phacc[row][w] = v;
            }
    }

    // ---- A partials: wave w sums srcs [16w, 16w+16) ----
    {
        float a_acc = 0.f;
        #pragma unroll
        for (int k2 = 0; k2 < 16; ++k2) {
            const int s = 16*w + k2;
            const unsigned short u = sV[s*72 + L];
            a_acc += al_s[s] * (float)__builtin_bit_cast(__bf16, u);
        }
        Apart[w][L] = a_acc;
    }
    __syncthreads();

    if (w == 0) {
        const float ph = phacc[L][0] + phacc[L][1] + phacc[L][2] + phacc[L][3];
        const float x0 = wsum(ph * xr_s[L][0]);
        const float x1 = wsum(ph * xr_s[L][1]);
        const float x2 = wsum(ph * xr_s[L][2]);
        if (L == 0) {
            Xout[d*3+0] = xd0 + x0;
            Xout[d*3+1] = xd1 + x1;
            Xout[d*3+2] = xd2 + x2;
        }
    } else if (w == 1) {
        Abuf[d*DIM + L] = Apart[0][L] + Apart[1][L] + Apart[2][L] + Apart[3][L];
    }
}

// ---------------------------------------------------------------------------
// K4: H_out = H + silu((A*A*H) @ phh_w1 + b1) @ phh_w2 + b2
// ---------------------------------------------------------------------------
__global__ __launch_bounds__(256) void k4_hout(
        const float* __restrict__ H, const float* __restrict__ Abuf,
        const float* __restrict__ w1, const float* __restrict__ b1,
        const float* __restrict__ w2, const float* __restrict__ b2,
        float* __restrict__ Hout) {
    const int w = threadIdx.x >> 6, L = threadIdx.x & 63;
    const int n = blockIdx.x * 4 + w;
    __shared__ float us[4][64];
    __shared__ float ss[4][64];
    const float h = H[n*DIM + L];
    const float a = Abuf[n*DIM + L];
    us[w][L] = a * a * h;
    __syncthreads();
    float z = b1[L];
    #pragma unroll 8
    for (int k = 0; k < 64; ++k) z += us[w][k] * w1[k*64 + L];
    ss[w][L] = silu_f(z);
    __syncthreads();
    float r = b2[L];
    #pragma unroll 8
    for (int j = 0; j < 64; ++j) r += ss[w][j] * w2[j*64 + L];
    Hout[n*DIM + L] = h + r;
}

// ---------------------------------------------------------------------------
extern "C" void kernel_launch(void* const* d_in, const int* in_sizes, int n_in,
                              void* d_out, int out_size, void* d_ws, size_t ws_size,
                              hipStream_t stream) {
    const float* X    = (const float*)d_in[1];
    const float* H    = (const float*)d_in[2];
    const float* xw   = (const float*)d_in[4];
    const float* qw1  = (const float*)d_in[5];
    const float* qw2  = (const float*)d_in[6];
    const float* kvw1 = (const float*)d_in[7];
    const float* kvw2 = (const float*)d_in[8];
    const float* qnw  = (const float*)d_in[9];
    const float* qnb  = (const float*)d_in[10];
    const float* knw  = (const float*)d_in[11];
    const float* knb  = (const float*)d_in[12];
    const float* pxw1 = (const float*)d_in[13];
    const float* pxw2 = (const float*)d_in[14];
    const float* phw1 = (const float*)d_in[15];
    const float* phb1 = (const float*)d_in[16];
    const float* phw2 = (const float*)d_in[17];
    const float* phb2 = (const float*)d_in[18];

    float* out = (float*)d_out;
    char*  ws  = (char*)d_ws;

    // ws layout: Xn[N*3] | Qn[N*64] | Pt[N*128] | Ab[N*64] | w2T bf16 | x1T bf16
    size_t off = 0;
    float* Xn = (float*)(ws + off); off += (size_t)NTOT*3*4;
    float* Qn = (float*)(ws + off); off += (size_t)NTOT*64*4;
    float* Pt = (float*)(ws + off); off += (size_t)NTOT*128*4;
    float* Ab = (float*)(ws + off); off += (size_t)NTOT*64*4;
    unsigned short* w2T = (unsigned short*)(ws + off); off += (size_t)128*136*2;
    unsigned short* x1T = (unsigned short*)(ws + off); off += (size_t)64*72*2;

    k0_prep<<<64, 256, 0, stream>>>(kvw2, pxw1, w2T, x1T);
    k1_xnorm<<<NB, 64, 0, stream>>>(X, xw, Xn);
    k2_node<<<NTOT/4, 256, 0, stream>>>(H, qw1, qw2, kvw1, qnw, qnb, Qn, Pt);
    k3_edge<<<NTOT, 256, 0, stream>>>(Xn, Qn, Pt, w2T, x1T, knw, knb,
                                      pxw2, kvw1, Ab, out);
    k4_hout<<<NTOT/4, 256, 0, stream>>>(H, Ab, phw1, phb1, phw2, phb2,
                                        out + NTOT*3);
}

// Round 3
// 225.419 us; speedup vs baseline: 4.1332x; 1.3866x over previous
//
#include <hip/hip_runtime.h>
#include <math.h>

// Problem constants (fixed by setup_inputs)
#define NB     128
#define NNODE  64
#define NTOT   8192
#define DIM    64
#define PSTR   136     // padded k-stride (bf16 elems) for Ptb / w2x rows

typedef __bf16 bf16x8 __attribute__((ext_vector_type(8)));
typedef float  f32x4  __attribute__((ext_vector_type(4)));

__device__ __forceinline__ float silu_f(float x) {
    return x / (1.0f + __expf(-x));
}

__device__ __forceinline__ unsigned short bf16bits(float f) {
    return __builtin_bit_cast(unsigned short, (__bf16)f);
}

__device__ __forceinline__ float wsum(float v) {
    #pragma unroll
    for (int m = 1; m < 64; m <<= 1) v += __shfl_xor(v, m, 64);
    return v;
}

// ---------------------------------------------------------------------------
// K0: prep + xnorm, grid 128 blocks x 256.
//  role T<128  : w2x[n][k] = kvw2[k][n]            (k = blockIdx.x)
//  role 128-191: w2x[128+n2][k] = sum_j kvw2[k][64+j]*phxw1[j][n2]  (Wfuse^T)
//  role 192-255: per-batch xnorm -> Xn4 (float4-padded)
// ---------------------------------------------------------------------------
__global__ __launch_bounds__(256) void k0_prep(
        const float* __restrict__ kvw2, const float* __restrict__ phxw1,
        const float* __restrict__ X, const float* __restrict__ xw,
        unsigned short* __restrict__ w2x, float* __restrict__ Xn4) {
    const int k = blockIdx.x;       // 0..127 : both k-index and batch id
    const int T = threadIdx.x;
    if (T < 128) {
        w2x[T*PSTR + k] = bf16bits(kvw2[k*128 + T]);
    } else if (T < 192) {
        const int n2 = T - 128;
        float acc = 0.f;
        #pragma unroll 8
        for (int j = 0; j < 64; ++j)
            acc += kvw2[k*128 + 64 + j] * phxw1[j*64 + n2];
        w2x[(128 + n2)*PSTR + k] = bf16bits(acc);
    } else {
        const int L = T - 192;      // lane in wave 3
        const int n = k*64 + L;
        const float x0 = X[n*3+0], x1 = X[n*3+1], x2 = X[n*3+2];
        const float nm = sqrtf(x0*x0 + x1*x1 + x2*x2);
        const float mean = wsum(nm) * (1.0f/64.0f);
        const float sc = xw[0] / (mean + 1e-5f);
        float4 o; o.x = x0*sc; o.y = x1*sc; o.z = x2*sc; o.w = 0.f;
        *(float4*)&Xn4[n*4] = o;
    }
}

// ---------------------------------------------------------------------------
// K2: per-node Qn = LN(silu(H@q_w1)@q_w2)*qnw+qnb; Ptb = bf16(H @ kv_w1[1:,:])
// ---------------------------------------------------------------------------
__global__ __launch_bounds__(256) void k2_node(
        const float* __restrict__ H,
        const float* __restrict__ qw1, const float* __restrict__ qw2,
        const float* __restrict__ kvw1,
        const float* __restrict__ qnw, const float* __restrict__ qnb,
        float* __restrict__ Qn, unsigned short* __restrict__ Ptb) {
    const int w = threadIdx.x >> 6, L = threadIdx.x & 63;
    const int n = blockIdx.x * 4 + w;
    __shared__ float hs[4][64];
    __shared__ float q1s[4][64];
    const float h = H[n*DIM + L];
    hs[w][L] = h;
    __syncthreads();
    float acc = 0.f;
    #pragma unroll 8
    for (int j = 0; j < 64; ++j) acc += hs[w][j] * qw1[j*64 + L];
    q1s[w][L] = silu_f(acc);
    __syncthreads();
    float a2 = 0.f;
    #pragma unroll 8
    for (int j = 0; j < 64; ++j) a2 += q1s[w][j] * qw2[j*64 + L];
    const float mu = wsum(a2) * (1.0f/64.0f);
    const float m2 = wsum(a2*a2) * (1.0f/64.0f);
    const float rstd = rsqrtf(m2 - mu*mu + 1e-5f);
    Qn[n*DIM + L] = (a2 - mu) * rstd * qnw[L] + qnb[L];
    float p0 = 0.f, p1 = 0.f;
    #pragma unroll 8
    for (int c = 0; c < 64; ++c) {
        const float hv = hs[w][c];
        p0 += hv * kvw1[(1+c)*128 + L];
        p1 += hv * kvw1[(1+c)*128 + 64 + L];
    }
    Ptb[(size_t)n*PSTR + L]      = bf16bits(p0);
    Ptb[(size_t)n*PSTR + 64 + L] = bf16bits(p1);
}

// ---------------------------------------------------------------------------
// K3: fused edge pipeline. Block = (graph, 16 dsts), 4 waves; each wave owns
// 4 dsts serially with NO cross-wave sync after staging. Per dst:
//   t A-frags built in regs from sPb -> K-pass (4ct) MFMA -> LN+score from
//   C-frags -> softmax in regs -> VG-pass (8ct: V|G) MFMA -> A-sum + phx
//   epilogue from C-frags. GEMM2 eliminated via Wfuse fused into B (cols
//   128..191). Fragment maps per learn_hip m89/m91.
// ---------------------------------------------------------------------------
__global__ __launch_bounds__(256, 2) void k3_edge(
        const float* __restrict__ Xn4, const float* __restrict__ Qn,
        const unsigned short* __restrict__ Ptb,
        const unsigned short* __restrict__ w2x,
        const float* __restrict__ kvw1,
        const float* __restrict__ knw, const float* __restrict__ knb,
        const float* __restrict__ pxw2,
        float* __restrict__ Abuf, float* __restrict__ Xout) {
    const int bid = blockIdx.x;
    const int g = bid >> 2, dgrp = bid & 3;
    const int T = threadIdx.x, w = T >> 6, L = T & 63;
    const int q = L >> 4, m = L & 15;

    __shared__ __align__(16) unsigned short sw2[192*PSTR];  // 52224 B
    __shared__ __align__(16) unsigned short sPb[64*PSTR];   // 17408 B
    __shared__ __align__(16) float sXn[64][4];              // 1024 B
    __shared__ __align__(16) float sQn[16][68];             // 4352 B
    __shared__ __align__(16) float xrw[4][64][4];           // 4096 B
    __shared__ float w0s[128];                              // 512 B
    __shared__ float knws[64], knbs[64], pxs[64];           // 768 B

    // ---- staging (once per block) ----
    {
        const uint4* s1 = (const uint4*)w2x;
        uint4* d1 = (uint4*)sw2;
        for (int idx = T; idx < 192*PSTR/8; idx += 256) d1[idx] = s1[idx];
        const uint4* s2 = (const uint4*)(Ptb + (size_t)g*64*PSTR);
        uint4* d2 = (uint4*)sPb;
        for (int idx = T; idx < 64*PSTR/8; idx += 256) d2[idx] = s2[idx];
        const float* qsrc = Qn + ((size_t)g*64 + dgrp*16)*64;
        for (int idx = T; idx < 1024; idx += 256)
            sQn[idx >> 6][idx & 63] = qsrc[idx];
        if (T < 64) *(float4*)&sXn[T][0] = *(const float4*)&Xn4[(g*64 + T)*4];
        if (T < 128) w0s[T] = kvw1[T];
        if (T < 64)            knws[T]       = knw[T];
        else if (T < 128)      knbs[T - 64]  = knb[T - 64];
        else if (T < 192)      pxs[T - 128]  = pxw2[T - 128];
    }
    __syncthreads();

    #pragma unroll 1
    for (int i = 0; i < 4; ++i) {
        const int dql = i*4 + w;            // 0..15 local dst
        const int dl  = dgrp*16 + dql;      // 0..63 in-graph dst
        const int d   = g*64 + dl;

        // ---- per-src geometry -> xrw[w][s] = {xr0,xr1,xr2,rd} ----
        asm volatile("s_waitcnt lgkmcnt(0)" ::: "memory");
        {
            const float4 xs  = *(const float4*)&sXn[L][0];
            const float4 xdv = *(const float4*)&sXn[dl][0];
            const float r0 = xs.x - xdv.x, r1 = xs.y - xdv.y, r2 = xs.z - xdv.z;
            const float rd = r0*r0 + r1*r1 + r2*r2;
            const float inv = 1.0f / (1.0f + sqrtf(rd + 1e-8f));
            float4 o; o.x = r0*inv; o.y = r1*inv; o.z = r2*inv; o.w = rd;
            *(float4*)&xrw[w][L][0] = o;
        }
        asm volatile("s_waitcnt lgkmcnt(0)" ::: "memory");

        // ---- build t A-fragments in registers ----
        bf16x8 af[4][4];
        float rdv[4];
        #pragma unroll
        for (int rt = 0; rt < 4; ++rt) rdv[rt] = xrw[w][rt*16 + m][3];
        #pragma unroll
        for (int ks = 0; ks < 4; ++ks) {
            float w0v[8];
            *(float4*)&w0v[0] = *(const float4*)&w0s[ks*32 + q*8];
            *(float4*)&w0v[4] = *(const float4*)&w0s[ks*32 + q*8 + 4];
            #pragma unroll
            for (int rt = 0; rt < 4; ++rt) {
                const bf16x8 pb = *(const bf16x8*)&sPb[(rt*16 + m)*PSTR + ks*32 + q*8];
                bf16x8 o;
                #pragma unroll
                for (int j = 0; j < 8; ++j) {
                    const float pf = (float)pb[j];
                    o[j] = (__bf16)silu_f(fmaf(rdv[rt], w0v[j], pf));
                }
                af[rt][ks] = o;
            }
        }

        // ---- K-pass: cols 0..63 ----
        f32x4 acc[4][4];
        #pragma unroll
        for (int ct = 0; ct < 4; ++ct)
            #pragma unroll
            for (int rt = 0; rt < 4; ++rt)
                acc[ct][rt] = (f32x4){0.f, 0.f, 0.f, 0.f};
        #pragma unroll
        for (int ks = 0; ks < 4; ++ks)
            #pragma unroll
            for (int ct = 0; ct < 4; ++ct) {
                const bf16x8 b = *(const bf16x8*)&sw2[(ct*16 + m)*PSTR + ks*32 + q*8];
                #pragma unroll
                for (int rt = 0; rt < 4; ++rt)
                    acc[ct][rt] = __builtin_amdgcn_mfma_f32_16x16x32_bf16(
                                      af[rt][ks], b, acc[ct][rt], 0, 0, 0);
            }

        // ---- LN(K)+score from C-frags ----
        float qdw[4], Sqdw = 0.f, Sqdb = 0.f;
        #pragma unroll
        for (int ct = 0; ct < 4; ++ct) {
            const float qd = sQn[dql][ct*16 + m];
            qdw[ct] = qd * knws[ct*16 + m];
            Sqdw += qdw[ct];
            Sqdb += qd * knbs[ct*16 + m];
        }
        #pragma unroll
        for (int sh = 1; sh < 16; sh <<= 1) {
            Sqdw += __shfl_xor(Sqdw, sh, 64);
            Sqdb += __shfl_xor(Sqdb, sh, 64);
        }
        float sc[4][4];
        #pragma unroll
        for (int rt = 0; rt < 4; ++rt)
            #pragma unroll
            for (int r = 0; r < 4; ++r) {
                float s1 = 0.f, s2 = 0.f, skq = 0.f;
                #pragma unroll
                for (int ct = 0; ct < 4; ++ct) {
                    const float kv = acc[ct][rt][r];
                    s1 += kv; s2 = fmaf(kv, kv, s2); skq = fmaf(kv, qdw[ct], skq);
                }
                #pragma unroll
                for (int sh = 1; sh < 16; sh <<= 1) {
                    s1  += __shfl_xor(s1,  sh, 64);
                    s2  += __shfl_xor(s2,  sh, 64);
                    skq += __shfl_xor(skq, sh, 64);
                }
                const float mu = s1 * (1.0f/64.0f);
                const float rstd = rsqrtf(s2 * (1.0f/64.0f) - mu*mu + 1e-5f);
                const float scv = (rstd * (skq - mu*Sqdw) + Sqdb) * 0.125f;
                const int row = rt*16 + q*4 + r;
                sc[rt][r] = (row == dl) ? -1e30f : scv;
            }

        // ---- softmax (rows distributed over q; identical across m) ----
        float mx = -1e30f;
        #pragma unroll
        for (int rt = 0; rt < 4; ++rt)
            #pragma unroll
            for (int r = 0; r < 4; ++r) mx = fmaxf(mx, sc[rt][r]);
        mx = fmaxf(mx, __shfl_xor(mx, 16, 64));
        mx = fmaxf(mx, __shfl_xor(mx, 32, 64));
        float al[4][4], S = 0.f;
        #pragma unroll
        for (int rt = 0; rt < 4; ++rt)
            #pragma unroll
            for (int r = 0; r < 4; ++r) {
                al[rt][r] = __expf(sc[rt][r] - mx);
                S += al[rt][r];
            }
        S += __shfl_xor(S, 16, 64);
        S += __shfl_xor(S, 32, 64);
        const float rS = 1.0f / S;
        #pragma unroll
        for (int rt = 0; rt < 4; ++rt)
            #pragma unroll
            for (int r = 0; r < 4; ++r) al[rt][r] *= rS;

        // ---- VG-pass: cols 64..191 (V | G=t@Wfuse) ----
        f32x4 vg[8][4];
        #pragma unroll
        for (int ct = 0; ct < 8; ++ct)
            #pragma unroll
            for (int rt = 0; rt < 4; ++rt)
                vg[ct][rt] = (f32x4){0.f, 0.f, 0.f, 0.f};
        #pragma unroll
        for (int ks = 0; ks < 4; ++ks)
            #pragma unroll
            for (int ct = 0; ct < 8; ++ct) {
                const bf16x8 b = *(const bf16x8*)&sw2[(64 + ct*16 + m)*PSTR + ks*32 + q*8];
                #pragma unroll
                for (int rt = 0; rt < 4; ++rt)
                    vg[ct][rt] = __builtin_amdgcn_mfma_f32_16x16x32_bf16(
                                     af[rt][ks], b, vg[ct][rt], 0, 0, 0);
            }

        // ---- A = sum_s alpha_s * V[s][:] (column sums over rows) ----
        #pragma unroll
        for (int ct = 0; ct < 4; ++ct) {
            float p = 0.f;
            #pragma unroll
            for (int rt = 0; rt < 4; ++rt)
                #pragma unroll
                for (int r = 0; r < 4; ++r)
                    p = fmaf(al[rt][r], vg[ct][rt][r], p);
            p += __shfl_xor(p, 16, 64);
            p += __shfl_xor(p, 32, 64);
            if (q == 0) Abuf[(size_t)d*64 + ct*16 + m] = p;
        }

        // ---- phx epilogue + X accumulation ----
        float pxc[4];
        #pragma unroll
        for (int ct = 0; ct < 4; ++ct) pxc[ct] = pxs[ct*16 + m];
        float xa0 = 0.f, xa1 = 0.f, xa2 = 0.f;
        #pragma unroll
        for (int rt = 0; rt < 4; ++rt)
            #pragma unroll
            for (int r = 0; r < 4; ++r) {
                float ph = 0.f;
                #pragma unroll
                for (int ct = 0; ct < 4; ++ct)
                    ph = fmaf(silu_f(al[rt][r] * vg[4 + ct][rt][r]), pxc[ct], ph);
                #pragma unroll
                for (int sh = 1; sh < 16; sh <<= 1) ph += __shfl_xor(ph, sh, 64);
                const float4 xr = *(const float4*)&xrw[w][rt*16 + q*4 + r][0];
                xa0 = fmaf(ph, xr.x, xa0);
                xa1 = fmaf(ph, xr.y, xa1);
                xa2 = fmaf(ph, xr.z, xa2);
            }
        xa0 += __shfl_xor(xa0, 16, 64); xa0 += __shfl_xor(xa0, 32, 64);
        xa1 += __shfl_xor(xa1, 16, 64); xa1 += __shfl_xor(xa1, 32, 64);
        xa2 += __shfl_xor(xa2, 16, 64); xa2 += __shfl_xor(xa2, 32, 64);
        if (L == 0) {
            const float4 xdv = *(const float4*)&sXn[dl][0];
            Xout[(size_t)d*3 + 0] = xdv.x + xa0;
            Xout[(size_t)d*3 + 1] = xdv.y + xa1;
            Xout[(size_t)d*3 + 2] = xdv.z + xa2;
        }
    }
}

// ---------------------------------------------------------------------------
// K4: H_out = H + silu((A*A*H) @ phh_w1 + b1) @ phh_w2 + b2
// ---------------------------------------------------------------------------
__global__ __launch_bounds__(256) void k4_hout(
        const float* __restrict__ H, const float* __restrict__ Abuf,
        const float* __restrict__ w1, const float* __restrict__ b1,
        const float* __restrict__ w2, const float* __restrict__ b2,
        float* __restrict__ Hout) {
    const int w = threadIdx.x >> 6, L = threadIdx.x & 63;
    const int n = blockIdx.x * 4 + w;
    __shared__ float us[4][64];
    __shared__ float ss[4][64];
    const float h = H[n*DIM + L];
    const float a = Abuf[n*DIM + L];
    us[w][L] = a * a * h;
    __syncthreads();
    float z = b1[L];
    #pragma unroll 8
    for (int k = 0; k < 64; ++k) z += us[w][k] * w1[k*64 + L];
    ss[w][L] = silu_f(z);
    __syncthreads();
    float r = b2[L];
    #pragma unroll 8
    for (int j = 0; j < 64; ++j) r += ss[w][j] * w2[j*64 + L];
    Hout[n*DIM + L] = h + r;
}

// ---------------------------------------------------------------------------
extern "C" void kernel_launch(void* const* d_in, const int* in_sizes, int n_in,
                              void* d_out, int out_size, void* d_ws, size_t ws_size,
                              hipStream_t stream) {
    const float* X    = (const float*)d_in[1];
    const float* H    = (const float*)d_in[2];
    const float* xw   = (const float*)d_in[4];
    const float* qw1  = (const float*)d_in[5];
    const float* qw2  = (const float*)d_in[6];
    const float* kvw1 = (const float*)d_in[7];
    const float* kvw2 = (const float*)d_in[8];
    const float* qnw  = (const float*)d_in[9];
    const float* qnb  = (const float*)d_in[10];
    const float* knw  = (const float*)d_in[11];
    const float* knb  = (const float*)d_in[12];
    const float* pxw1 = (const float*)d_in[13];
    const float* pxw2 = (const float*)d_in[14];
    const float* phw1 = (const float*)d_in[15];
    const float* phb1 = (const float*)d_in[16];
    const float* phw2 = (const float*)d_in[17];
    const float* phb2 = (const float*)d_in[18];

    float* out = (float*)d_out;
    char*  ws  = (char*)d_ws;

    // ws: Xn4[N*4] | Qn[N*64] | Ptb[N*136 bf16] | Ab[N*64] | w2x[192*136 bf16]
    size_t off = 0;
    float* Xn4 = (float*)(ws + off);          off += (size_t)NTOT*4*4;
    float* Qn  = (float*)(ws + off);          off += (size_t)NTOT*64*4;
    unsigned short* Ptb = (unsigned short*)(ws + off); off += (size_t)NTOT*PSTR*2;
    float* Ab  = (float*)(ws + off);          off += (size_t)NTOT*64*4;
    unsigned short* w2x = (unsigned short*)(ws + off); off += (size_t)192*PSTR*2;

    k0_prep<<<128, 256, 0, stream>>>(kvw2, pxw1, X, xw, w2x, Xn4);
    k2_node<<<NTOT/4, 256, 0, stream>>>(H, qw1, qw2, kvw1, qnw, qnb, Qn, Ptb);
    k3_edge<<<512, 256, 0, stream>>>(Xn4, Qn, Ptb, w2x, kvw1, knw, knb,
                                     pxw2, Ab, out);
    k4_hout<<<NTOT/4, 256, 0, stream>>>(H, Ab, phw1, phb1, phw2, phb2,
                                        out + NTOT*3);
}

// Round 4
// 199.076 us; speedup vs baseline: 4.6802x; 1.1323x over previous
//
#include <hip/hip_runtime.h>
#include <math.h>

// Problem constants (fixed by setup_inputs)
#define NB     128
#define NNODE  64
#define NTOT   8192
#define DIM    64
#define PSTR   136     // padded k-stride (bf16 elems) for Ptb / w2x rows
#define WS72   72      // padded k-stride for small 64-k weight transposes

typedef __bf16 bf16x8 __attribute__((ext_vector_type(8)));
typedef float  f32x4  __attribute__((ext_vector_type(4)));

__device__ __forceinline__ float silu_f(float x) {
    return x / (1.0f + __expf(-x));
}

__device__ __forceinline__ unsigned short bf16bits(float f) {
    return __builtin_bit_cast(unsigned short, (__bf16)f);
}

__device__ __forceinline__ bf16x8 to_bf16x8(const float* v) {
    bf16x8 o;
    #pragma unroll
    for (int j = 0; j < 8; ++j) o[j] = (__bf16)v[j];
    return o;
}

__device__ __forceinline__ float wsum(float v) {
    #pragma unroll
    for (int m = 1; m < 64; m <<= 1) v += __shfl_xor(v, m, 64);
    return v;
}

// ---------------------------------------------------------------------------
// K0: prep transposed bf16 weights + xnorm. grid 128 x 256.
//  All w*T layouts: wT[n][k] = w[k][n], row stride WS72 (or PSTR for w2x).
// ---------------------------------------------------------------------------
__global__ __launch_bounds__(256) void k0_prep(
        const float* __restrict__ kvw2, const float* __restrict__ phxw1,
        const float* __restrict__ X, const float* __restrict__ xw,
        const float* __restrict__ qw1, const float* __restrict__ qw2,
        const float* __restrict__ kvw1,
        const float* __restrict__ phh1, const float* __restrict__ phh2,
        unsigned short* __restrict__ w2x, float* __restrict__ Xn4,
        unsigned short* __restrict__ qw1T, unsigned short* __restrict__ qw2T,
        unsigned short* __restrict__ kvw1T,
        unsigned short* __restrict__ phh1T, unsigned short* __restrict__ phh2T) {
    const int k = blockIdx.x;       // 0..127 : k-index and batch id
    const int T = threadIdx.x;
    if (T < 128) {
        w2x[T*PSTR + k] = bf16bits(kvw2[k*128 + T]);
    } else if (T < 192) {
        const int n2 = T - 128;
        float acc = 0.f;
        #pragma unroll 8
        for (int j = 0; j < 64; ++j)
            acc += kvw2[k*128 + 64 + j] * phxw1[j*64 + n2];
        w2x[(128 + n2)*PSTR + k] = bf16bits(acc);
    } else {
        const int L = T - 192;      // wave 3: xnorm for batch k
        const int n = k*64 + L;
        const float x0 = X[n*3+0], x1 = X[n*3+1], x2 = X[n*3+2];
        const float nm = sqrtf(x0*x0 + x1*x1 + x2*x2);
        const float mean = wsum(nm) * (1.0f/64.0f);
        const float sc = xw[0] / (mean + 1e-5f);
        float4 o; o.x = x0*sc; o.y = x1*sc; o.z = x2*sc; o.w = 0.f;
        *(float4*)&Xn4[n*4] = o;
    }
    if (k < 64) {
        if (T < 128) kvw1T[T*WS72 + k] = bf16bits(kvw1[(1+k)*128 + T]);
    } else {
        const int kk = k - 64;
        if (T < 64)       qw1T[T*WS72 + kk]        = bf16bits(qw1[kk*64 + T]);
        else if (T < 128) qw2T[(T-64)*WS72 + kk]   = bf16bits(qw2[kk*64 + (T-64)]);
        else if (T < 192) phh1T[(T-128)*WS72 + kk] = bf16bits(phh1[kk*64 + (T-128)]);
        else              phh2T[(T-192)*WS72 + kk] = bf16bits(phh2[kk*64 + (T-192)]);
    }
}

// ---------------------------------------------------------------------------
// K2 (MFMA): per 64-node tile, wave w owns rows [16w,16w+16):
//   Z = silu(H@qw1) -> LDS -> Z@qw2 -> LN -> Qn ; P = H@kvw1[1:] -> Ptb bf16
// ---------------------------------------------------------------------------
__global__ __launch_bounds__(256) void k2_node(
        const float* __restrict__ H,
        const unsigned short* __restrict__ qw1T,
        const unsigned short* __restrict__ qw2T,
        const unsigned short* __restrict__ kvw1T,
        const float* __restrict__ qnw, const float* __restrict__ qnb,
        float* __restrict__ Qn, unsigned short* __restrict__ Ptb) {
    const int nb = blockIdx.x * 64;
    const int T = threadIdx.x, w = T >> 6, L = T & 63;
    const int q = L >> 4, m = L & 15;
    __shared__ __align__(16) unsigned short zb[64*WS72];

    // A-frags of H for rows 16w+m
    bf16x8 hf[2];
    #pragma unroll
    for (int ks = 0; ks < 2; ++ks) {
        float v[8];
        *(float4*)&v[0] = *(const float4*)&H[(size_t)(nb + w*16 + m)*64 + ks*32 + q*8];
        *(float4*)&v[4] = *(const float4*)&H[(size_t)(nb + w*16 + m)*64 + ks*32 + q*8 + 4];
        hf[ks] = to_bf16x8(v);
    }

    // GEMM1: Z = H @ qw1
    f32x4 acc[4];
    #pragma unroll
    for (int ct = 0; ct < 4; ++ct) acc[ct] = (f32x4){0.f,0.f,0.f,0.f};
    #pragma unroll
    for (int ks = 0; ks < 2; ++ks)
        #pragma unroll
        for (int ct = 0; ct < 4; ++ct) {
            const bf16x8 b = *(const bf16x8*)&qw1T[(ct*16 + m)*WS72 + ks*32 + q*8];
            acc[ct] = __builtin_amdgcn_mfma_f32_16x16x32_bf16(hf[ks], b, acc[ct], 0, 0, 0);
        }
    #pragma unroll
    for (int ct = 0; ct < 4; ++ct)
        #pragma unroll
        for (int r = 0; r < 4; ++r)
            zb[(w*16 + q*4 + r)*WS72 + ct*16 + m] = bf16bits(silu_f(acc[ct][r]));
    __syncthreads();

    // GEMM2: Z2 = Zs @ qw2, then LN
    bf16x8 zf[2];
    #pragma unroll
    for (int ks = 0; ks < 2; ++ks)
        zf[ks] = *(const bf16x8*)&zb[(w*16 + m)*WS72 + ks*32 + q*8];
    #pragma unroll
    for (int ct = 0; ct < 4; ++ct) acc[ct] = (f32x4){0.f,0.f,0.f,0.f};
    #pragma unroll
    for (int ks = 0; ks < 2; ++ks)
        #pragma unroll
        for (int ct = 0; ct < 4; ++ct) {
            const bf16x8 b = *(const bf16x8*)&qw2T[(ct*16 + m)*WS72 + ks*32 + q*8];
            acc[ct] = __builtin_amdgcn_mfma_f32_16x16x32_bf16(zf[ks], b, acc[ct], 0, 0, 0);
        }
    float qnwv[4], qnbv[4];
    #pragma unroll
    for (int ct = 0; ct < 4; ++ct) { qnwv[ct] = qnw[ct*16+m]; qnbv[ct] = qnb[ct*16+m]; }
    #pragma unroll
    for (int r = 0; r < 4; ++r) {
        float s1 = 0.f, s2 = 0.f;
        #pragma unroll
        for (int ct = 0; ct < 4; ++ct) {
            const float z = acc[ct][r];
            s1 += z; s2 = fmaf(z, z, s2);
        }
        #pragma unroll
        for (int sh = 1; sh < 16; sh <<= 1) {
            s1 += __shfl_xor(s1, sh, 64);
            s2 += __shfl_xor(s2, sh, 64);
        }
        const float mu = s1 * (1.0f/64.0f);
        const float rstd = rsqrtf(s2 * (1.0f/64.0f) - mu*mu + 1e-5f);
        const int row = nb + w*16 + q*4 + r;
        #pragma unroll
        for (int ct = 0; ct < 4; ++ct)
            Qn[(size_t)row*64 + ct*16 + m] = (acc[ct][r] - mu)*rstd*qnwv[ct] + qnbv[ct];
    }

    // GEMM3: P = H @ kvw1[1:], two 64-col halves
    #pragma unroll
    for (int ph = 0; ph < 2; ++ph) {
        #pragma unroll
        for (int ct = 0; ct < 4; ++ct) acc[ct] = (f32x4){0.f,0.f,0.f,0.f};
        #pragma unroll
        for (int ks = 0; ks < 2; ++ks)
            #pragma unroll
            for (int ct = 0; ct < 4; ++ct) {
                const bf16x8 b = *(const bf16x8*)&kvw1T[(ph*64 + ct*16 + m)*WS72 + ks*32 + q*8];
                acc[ct] = __builtin_amdgcn_mfma_f32_16x16x32_bf16(hf[ks], b, acc[ct], 0, 0, 0);
            }
        #pragma unroll
        for (int ct = 0; ct < 4; ++ct)
            #pragma unroll
            for (int r = 0; r < 4; ++r)
                Ptb[(size_t)(nb + w*16 + q*4 + r)*PSTR + ph*64 + ct*16 + m]
                    = bf16bits(acc[ct][r]);
    }
}

// ---------------------------------------------------------------------------
// K3: fused edge pipeline (split K/V/G passes, one reused accumulator).
// ---------------------------------------------------------------------------
__global__ __launch_bounds__(256, 2) void k3_edge(
        const float* __restrict__ Xn4, const float* __restrict__ Qn,
        const unsigned short* __restrict__ Ptb,
        const unsigned short* __restrict__ w2x,
        const float* __restrict__ kvw1,
        const float* __restrict__ knw, const float* __restrict__ knb,
        const float* __restrict__ pxw2,
        float* __restrict__ Abuf, float* __restrict__ Xout) {
    const int bid = blockIdx.x;
    const int g = bid >> 2, dgrp = bid & 3;
    const int T = threadIdx.x, w = T >> 6, L = T & 63;
    const int q = L >> 4, m = L & 15;

    __shared__ __align__(16) unsigned short sw2[192*PSTR];  // 52224 B
    __shared__ __align__(16) unsigned short sPb[64*PSTR];   // 17408 B
    __shared__ __align__(16) float sXn[64][4];
    __shared__ __align__(16) float sQn[16][68];
    __shared__ __align__(16) float xrw[4][64][4];
    __shared__ float w0s[128];
    __shared__ float knws[64], knbs[64], pxs[64];

    // ---- staging (once per block) ----
    {
        const uint4* s1 = (const uint4*)w2x;
        uint4* d1 = (uint4*)sw2;
        for (int idx = T; idx < 192*PSTR/8; idx += 256) d1[idx] = s1[idx];
        const uint4* s2 = (const uint4*)(Ptb + (size_t)g*64*PSTR);
        uint4* d2 = (uint4*)sPb;
        for (int idx = T; idx < 64*PSTR/8; idx += 256) d2[idx] = s2[idx];
        const float* qsrc = Qn + ((size_t)g*64 + dgrp*16)*64;
        for (int idx = T; idx < 1024; idx += 256)
            sQn[idx >> 6][idx & 63] = qsrc[idx];
        if (T < 64) *(float4*)&sXn[T][0] = *(const float4*)&Xn4[(g*64 + T)*4];
        if (T < 128) w0s[T] = kvw1[T];
        if (T < 64)            knws[T]       = knw[T];
        else if (T < 128)      knbs[T - 64]  = knb[T - 64];
        else if (T < 192)      pxs[T - 128]  = pxw2[T - 128];
    }
    __syncthreads();

    #pragma unroll 1
    for (int i = 0; i < 4; ++i) {
        const int dql = i*4 + w;
        const int dl  = dgrp*16 + dql;
        const int d   = g*64 + dl;

        // ---- per-src geometry ----
        asm volatile("s_waitcnt lgkmcnt(0)" ::: "memory");
        {
            const float4 xs  = *(const float4*)&sXn[L][0];
            const float4 xdv = *(const float4*)&sXn[dl][0];
            const float r0 = xs.x - xdv.x, r1 = xs.y - xdv.y, r2 = xs.z - xdv.z;
            const float rd = r0*r0 + r1*r1 + r2*r2;
            const float inv = 1.0f / (1.0f + sqrtf(rd + 1e-8f));
            float4 o; o.x = r0*inv; o.y = r1*inv; o.z = r2*inv; o.w = rd;
            *(float4*)&xrw[w][L][0] = o;
        }
        asm volatile("s_waitcnt lgkmcnt(0)" ::: "memory");

        // ---- build t A-fragments in registers ----
        bf16x8 af[4][4];
        float rdv[4];
        #pragma unroll
        for (int rt = 0; rt < 4; ++rt) rdv[rt] = xrw[w][rt*16 + m][3];
        #pragma unroll
        for (int ks = 0; ks < 4; ++ks) {
            float w0v[8];
            *(float4*)&w0v[0] = *(const float4*)&w0s[ks*32 + q*8];
            *(float4*)&w0v[4] = *(const float4*)&w0s[ks*32 + q*8 + 4];
            #pragma unroll
            for (int rt = 0; rt < 4; ++rt) {
                const bf16x8 pb = *(const bf16x8*)&sPb[(rt*16 + m)*PSTR + ks*32 + q*8];
                bf16x8 o;
                #pragma unroll
                for (int j = 0; j < 8; ++j) {
                    const float pf = (float)pb[j];
                    o[j] = (__bf16)silu_f(fmaf(rdv[rt], w0v[j], pf));
                }
                af[rt][ks] = o;
            }
        }

        f32x4 acc[4][4];

        // ---- K-pass: cols 0..63 ----
        #pragma unroll
        for (int ct = 0; ct < 4; ++ct)
            #pragma unroll
            for (int rt = 0; rt < 4; ++rt)
                acc[ct][rt] = (f32x4){0.f, 0.f, 0.f, 0.f};
        #pragma unroll
        for (int ks = 0; ks < 4; ++ks)
            #pragma unroll
            for (int ct = 0; ct < 4; ++ct) {
                const bf16x8 b = *(const bf16x8*)&sw2[(ct*16 + m)*PSTR + ks*32 + q*8];
                #pragma unroll
                for (int rt = 0; rt < 4; ++rt)
                    acc[ct][rt] = __builtin_amdgcn_mfma_f32_16x16x32_bf16(
                                      af[rt][ks], b, acc[ct][rt], 0, 0, 0);
            }

        // ---- LN(K)+score from C-frags ----
        float qdw[4], Sqdw = 0.f, Sqdb = 0.f;
        #pragma unroll
        for (int ct = 0; ct < 4; ++ct) {
            const float qd = sQn[dql][ct*16 + m];
            qdw[ct] = qd * knws[ct*16 + m];
            Sqdw += qdw[ct];
            Sqdb += qd * knbs[ct*16 + m];
        }
        #pragma unroll
        for (int sh = 1; sh < 16; sh <<= 1) {
            Sqdw += __shfl_xor(Sqdw, sh, 64);
            Sqdb += __shfl_xor(Sqdb, sh, 64);
        }
        float sc[4][4];
        #pragma unroll
        for (int rt = 0; rt < 4; ++rt)
            #pragma unroll
            for (int r = 0; r < 4; ++r) {
                float s1 = 0.f, s2 = 0.f, skq = 0.f;
                #pragma unroll
                for (int ct = 0; ct < 4; ++ct) {
                    const float kv = acc[ct][rt][r];
                    s1 += kv; s2 = fmaf(kv, kv, s2); skq = fmaf(kv, qdw[ct], skq);
                }
                #pragma unroll
                for (int sh = 1; sh < 16; sh <<= 1) {
                    s1  += __shfl_xor(s1,  sh, 64);
                    s2  += __shfl_xor(s2,  sh, 64);
                    skq += __shfl_xor(skq, sh, 64);
                }
                const float mu = s1 * (1.0f/64.0f);
                const float rstd = rsqrtf(s2 * (1.0f/64.0f) - mu*mu + 1e-5f);
                const float scv = (rstd * (skq - mu*Sqdw) + Sqdb) * 0.125f;
                const int row = rt*16 + q*4 + r;
                sc[rt][r] = (row == dl) ? -1e30f : scv;
            }

        // ---- softmax ----
        float mx = -1e30f;
        #pragma unroll
        for (int rt = 0; rt < 4; ++rt)
            #pragma unroll
            for (int r = 0; r < 4; ++r) mx = fmaxf(mx, sc[rt][r]);
        mx = fmaxf(mx, __shfl_xor(mx, 16, 64));
        mx = fmaxf(mx, __shfl_xor(mx, 32, 64));
        float al[4][4], S = 0.f;
        #pragma unroll
        for (int rt = 0; rt < 4; ++rt)
            #pragma unroll
            for (int r = 0; r < 4; ++r) {
                al[rt][r] = __expf(sc[rt][r] - mx);
                S += al[rt][r];
            }
        S += __shfl_xor(S, 16, 64);
        S += __shfl_xor(S, 32, 64);
        const float rS = 1.0f / S;
        #pragma unroll
        for (int rt = 0; rt < 4; ++rt)
            #pragma unroll
            for (int r = 0; r < 4; ++r) al[rt][r] *= rS;

        // ---- V-pass: cols 64..127 ----
        #pragma unroll
        for (int ct = 0; ct < 4; ++ct)
            #pragma unroll
            for (int rt = 0; rt < 4; ++rt)
                acc[ct][rt] = (f32x4){0.f, 0.f, 0.f, 0.f};
        #pragma unroll
        for (int ks = 0; ks < 4; ++ks)
            #pragma unroll
            for (int ct = 0; ct < 4; ++ct) {
                const bf16x8 b = *(const bf16x8*)&sw2[(64 + ct*16 + m)*PSTR + ks*32 + q*8];
                #pragma unroll
                for (int rt = 0; rt < 4; ++rt)
                    acc[ct][rt] = __builtin_amdgcn_mfma_f32_16x16x32_bf16(
                                      af[rt][ks], b, acc[ct][rt], 0, 0, 0);
            }
        // A = sum_s alpha_s * V[s][:]
        #pragma unroll
        for (int ct = 0; ct < 4; ++ct) {
            float p = 0.f;
            #pragma unroll
            for (int rt = 0; rt < 4; ++rt)
                #pragma unroll
                for (int r = 0; r < 4; ++r)
                    p = fmaf(al[rt][r], acc[ct][rt][r], p);
            p += __shfl_xor(p, 16, 64);
            p += __shfl_xor(p, 32, 64);
            if (q == 0) Abuf[(size_t)d*64 + ct*16 + m] = p;
        }

        // ---- G-pass: cols 128..191 ----
        #pragma unroll
        for (int ct = 0; ct < 4; ++ct)
            #pragma unroll
            for (int rt = 0; rt < 4; ++rt)
                acc[ct][rt] = (f32x4){0.f, 0.f, 0.f, 0.f};
        #pragma unroll
        for (int ks = 0; ks < 4; ++ks)
            #pragma unroll
            for (int ct = 0; ct < 4; ++ct) {
                const bf16x8 b = *(const bf16x8*)&sw2[(128 + ct*16 + m)*PSTR + ks*32 + q*8];
                #pragma unroll
                for (int rt = 0; rt < 4; ++rt)
                    acc[ct][rt] = __builtin_amdgcn_mfma_f32_16x16x32_bf16(
                                      af[rt][ks], b, acc[ct][rt], 0, 0, 0);
            }

        // ---- phx epilogue + X accumulation ----
        float pxc[4];
        #pragma unroll
        for (int ct = 0; ct < 4; ++ct) pxc[ct] = pxs[ct*16 + m];
        float xa0 = 0.f, xa1 = 0.f, xa2 = 0.f;
        #pragma unroll
        for (int rt = 0; rt < 4; ++rt)
            #pragma unroll
            for (int r = 0; r < 4; ++r) {
                float ph = 0.f;
                #pragma unroll
                for (int ct = 0; ct < 4; ++ct)
                    ph = fmaf(silu_f(al[rt][r] * acc[ct][rt][r]), pxc[ct], ph);
                #pragma unroll
                for (int sh = 1; sh < 16; sh <<= 1) ph += __shfl_xor(ph, sh, 64);
                const float4 xr = *(const float4*)&xrw[w][rt*16 + q*4 + r][0];
                xa0 = fmaf(ph, xr.x, xa0);
                xa1 = fmaf(ph, xr.y, xa1);
                xa2 = fmaf(ph, xr.z, xa2);
            }
        xa0 += __shfl_xor(xa0, 16, 64); xa0 += __shfl_xor(xa0, 32, 64);
        xa1 += __shfl_xor(xa1, 16, 64); xa1 += __shfl_xor(xa1, 32, 64);
        xa2 += __shfl_xor(xa2, 16, 64); xa2 += __shfl_xor(xa2, 32, 64);
        if (L == 0) {
            const float4 xdv = *(const float4*)&sXn[dl][0];
            Xout[(size_t)d*3 + 0] = xdv.x + xa0;
            Xout[(size_t)d*3 + 1] = xdv.y + xa1;
            Xout[(size_t)d*3 + 2] = xdv.z + xa2;
        }
    }
}

// ---------------------------------------------------------------------------
// K4 (MFMA): H_out = H + silu((A*A*H)@phh1 + b1)@phh2 + b2, 64-node tiles.
// ---------------------------------------------------------------------------
__global__ __launch_bounds__(256) void k4_hout(
        const float* __restrict__ H, const float* __restrict__ Abuf,
        const unsigned short* __restrict__ phh1T, const float* __restrict__ b1,
        const unsigned short* __restrict__ phh2T, const float* __restrict__ b2,
        float* __restrict__ Hout) {
    const int nb = blockIdx.x * 64;
    const int T = threadIdx.x, w = T >> 6, L = T & 63;
    const int q = L >> 4, m = L & 15;
    __shared__ __align__(16) unsigned short zb[64*WS72];

    bf16x8 uf[2];
    #pragma unroll
    for (int ks = 0; ks < 2; ++ks) {
        const size_t base = (size_t)(nb + w*16 + m)*64 + ks*32 + q*8;
        float a[8], h[8], v[8];
        *(float4*)&a[0] = *(const float4*)&Abuf[base];
        *(float4*)&a[4] = *(const float4*)&Abuf[base + 4];
        *(float4*)&h[0] = *(const float4*)&H[base];
        *(float4*)&h[4] = *(const float4*)&H[base + 4];
        #pragma unroll
        for (int j = 0; j < 8; ++j) v[j] = a[j]*a[j]*h[j];
        uf[ks] = to_bf16x8(v);
    }

    f32x4 acc[4];
    #pragma unroll
    for (int ct = 0; ct < 4; ++ct) acc[ct] = (f32x4){0.f,0.f,0.f,0.f};
    #pragma unroll
    for (int ks = 0; ks < 2; ++ks)
        #pragma unroll
        for (int ct = 0; ct < 4; ++ct) {
            const bf16x8 b = *(const bf16x8*)&phh1T[(ct*16 + m)*WS72 + ks*32 + q*8];
            acc[ct] = __builtin_amdgcn_mfma_f32_16x16x32_bf16(uf[ks], b, acc[ct], 0, 0, 0);
        }
    #pragma unroll
    for (int ct = 0; ct < 4; ++ct) {
        const float bv = b1[ct*16 + m];
        #pragma unroll
        for (int r = 0; r < 4; ++r)
            zb[(w*16 + q*4 + r)*WS72 + ct*16 + m] = bf16bits(silu_f(acc[ct][r] + bv));
    }
    __syncthreads();

    bf16x8 zf[2];
    #pragma unroll
    for (int ks = 0; ks < 2; ++ks)
        zf[ks] = *(const bf16x8*)&zb[(w*16 + m)*WS72 + ks*32 + q*8];
    #pragma unroll
    for (int ct = 0; ct < 4; ++ct) acc[ct] = (f32x4){0.f,0.f,0.f,0.f};
    #pragma unroll
    for (int ks = 0; ks < 2; ++ks)
        #pragma unroll
        for (int ct = 0; ct < 4; ++ct) {
            const bf16x8 b = *(const bf16x8*)&phh2T[(ct*16 + m)*WS72 + ks*32 + q*8];
            acc[ct] = __builtin_amdgcn_mfma_f32_16x16x32_bf16(zf[ks], b, acc[ct], 0, 0, 0);
        }
    #pragma unroll
    for (int ct = 0; ct < 4; ++ct) {
        const float bv = b2[ct*16 + m];
        #pragma unroll
        for (int r = 0; r < 4; ++r) {
            const size_t idx = (size_t)(nb + w*16 + q*4 + r)*64 + ct*16 + m;
            Hout[idx] = H[idx] + acc[ct][r] + bv;
        }
    }
}

// ---------------------------------------------------------------------------
extern "C" void kernel_launch(void* const* d_in, const int* in_sizes, int n_in,
                              void* d_out, int out_size, void* d_ws, size_t ws_size,
                              hipStream_t stream) {
    const float* X    = (const float*)d_in[1];
    const float* H    = (const float*)d_in[2];
    const float* xw   = (const float*)d_in[4];
    const float* qw1  = (const float*)d_in[5];
    const float* qw2  = (const float*)d_in[6];
    const float* kvw1 = (const float*)d_in[7];
    const float* kvw2 = (const float*)d_in[8];
    const float* qnw  = (const float*)d_in[9];
    const float* qnb  = (const float*)d_in[10];
    const float* knw  = (const float*)d_in[11];
    const float* knb  = (const float*)d_in[12];
    const float* pxw1 = (const float*)d_in[13];
    const float* pxw2 = (const float*)d_in[14];
    const float* phw1 = (const float*)d_in[15];
    const float* phb1 = (const float*)d_in[16];
    const float* phw2 = (const float*)d_in[17];
    const float* phb2 = (const float*)d_in[18];

    float* out = (float*)d_out;
    char*  ws  = (char*)d_ws;

    size_t off = 0;
    float* Xn4 = (float*)(ws + off);          off += (size_t)NTOT*4*4;
    float* Qn  = (float*)(ws + off);          off += (size_t)NTOT*64*4;
    unsigned short* Ptb = (unsigned short*)(ws + off); off += (size_t)NTOT*PSTR*2;
    float* Ab  = (float*)(ws + off);          off += (size_t)NTOT*64*4;
    unsigned short* w2x   = (unsigned short*)(ws + off); off += (size_t)192*PSTR*2;
    unsigned short* qw1T  = (unsigned short*)(ws + off); off += (size_t)64*WS72*2;
    unsigned short* qw2T  = (unsigned short*)(ws + off); off += (size_t)64*WS72*2;
    unsigned short* kvw1T = (unsigned short*)(ws + off); off += (size_t)128*WS72*2;
    unsigned short* phh1T = (unsigned short*)(ws + off); off += (size_t)64*WS72*2;
    unsigned short* phh2T = (unsigned short*)(ws + off); off += (size_t)64*WS72*2;

    k0_prep<<<128, 256, 0, stream>>>(kvw2, pxw1, X, xw, qw1, qw2, kvw1,
                                     phw1, phw2, w2x, Xn4,
                                     qw1T, qw2T, kvw1T, phh1T, phh2T);
    k2_node<<<128, 256, 0, stream>>>(H, qw1T, qw2T, kvw1T, qnw, qnb, Qn, Ptb);
    k3_edge<<<512, 256, 0, stream>>>(Xn4, Qn, Ptb, w2x, kvw1, knw, knb,
                                     pxw2, Ab, out);
    k4_hout<<<128, 256, 0, stream>>>(H, Ab, phh1T, phb1, phh2T, phb2,
                                     out + NTOT*3);
}